// Round 1
// baseline (722.447 us; speedup 1.0000x reference)
//
#include <hip/hip_runtime.h>

#define S_ 384
#define D_ 384
#define SD_ (384*384)

// output offsets (floats) in return order
#define OUT_EV 0
#define OUT_FS 56623104
#define OUT_IE 113246208
#define OUT_YM 113246209
#define OUT_FC 113246210
#define OUT_GI 113246594
#define OUT_CO 113246595
#define OUT_CH 113246979
#define OUT_TP 113246980

__device__ __forceinline__ float waveSum(float v){
  v += __shfl_down(v,32); v += __shfl_down(v,16); v += __shfl_down(v,8);
  v += __shfl_down(v,4);  v += __shfl_down(v,2);  v += __shfl_down(v,1);
  return v;
}
__device__ __forceinline__ float waveMax(float v){
  v = fmaxf(v,__shfl_down(v,32)); v = fmaxf(v,__shfl_down(v,16)); v = fmaxf(v,__shfl_down(v,8));
  v = fmaxf(v,__shfl_down(v,4));  v = fmaxf(v,__shfl_down(v,2));  v = fmaxf(v,__shfl_down(v,1));
  return v;
}

// K1: gradients ga/gb, row means -> cm, sum(q^2). grid 384 x 128
__global__ void k_prep(const float* __restrict__ q, const float* __restrict__ k,
                       float* __restrict__ ga, float* __restrict__ gb,
                       float* __restrict__ cm, double* __restrict__ acc){
  int s = blockIdx.x, t = threadIdx.x;
  const float* qs = q + s*D_;
  const float* ks = k + s*D_;
  float sq=0.f, sk=0.f, sq2=0.f;
  for (int d=t; d<D_; d+=128){ float a=qs[d], b=ks[d]; sq+=a; sk+=b; sq2+=a*a; }
  sq = waveSum(sq); sk = waveSum(sk); sq2 = waveSum(sq2);
  __shared__ float red[3][2];
  int wid=t>>6, lane=t&63;
  if (lane==0){ red[0][wid]=sq; red[1][wid]=sk; red[2][wid]=sq2; }
  __syncthreads();
  float qmean = (red[0][0]+red[0][1]) * (1.0f/D_);
  float kmean = (red[1][0]+red[1][1]) * (1.0f/D_);
  if (t==0) atomicAdd(&acc[0], (double)(red[2][0]+red[2][1]));
  int sm = (s==0)?0:s-1, sp=(s==S_-1)?S_-1:s+1;
  float sc = (s==0 || s==S_-1) ? 1.f : 0.5f;
  const float* qm=q+sm*D_; const float* qp=q+sp*D_;
  const float* km=k+sm*D_; const float* kp=k+sp*D_;
  for (int d=t; d<D_; d+=128){
    ga[s*D_+d] = (qp[d]-qm[d])*sc;
    gb[s*D_+d] = (kp[d]-km[d])*sc;
    cm[s*D_+d] = qs[d]*kmean - ks[d]*qmean;
  }
}

// K2: cov_q = ga + q@W, cov_k = gb + k@W. grid 96 x 384, 4 rows/block
__global__ void k_cov(const float* __restrict__ q, const float* __restrict__ kk,
                      const float* __restrict__ W,
                      const float* __restrict__ ga, const float* __restrict__ gb,
                      float* __restrict__ covq, float* __restrict__ covk){
  int b=blockIdx.x, t=threadIdx.x, s0=b*4;
  __shared__ float lq[4][D_], lk[4][D_];
  for (int idx=t; idx<4*D_; idx+=384){
    int r=idx/D_, e=idx-r*D_;
    lq[r][e]=q[(s0+r)*D_+e];
    lk[r][e]=kk[(s0+r)*D_+e];
  }
  __syncthreads();
  float aq0=0,aq1=0,aq2=0,aq3=0, ak0=0,ak1=0,ak2=0,ak3=0;
  for (int e=0;e<D_;e+=4){
    float w0=W[(e+0)*D_+t], w1=W[(e+1)*D_+t], w2=W[(e+2)*D_+t], w3=W[(e+3)*D_+t];
    float4 x;
    x=*(const float4*)&lq[0][e]; aq0 += x.x*w0 + x.y*w1 + x.z*w2 + x.w*w3;
    x=*(const float4*)&lq[1][e]; aq1 += x.x*w0 + x.y*w1 + x.z*w2 + x.w*w3;
    x=*(const float4*)&lq[2][e]; aq2 += x.x*w0 + x.y*w1 + x.z*w2 + x.w*w3;
    x=*(const float4*)&lq[3][e]; aq3 += x.x*w0 + x.y*w1 + x.z*w2 + x.w*w3;
    x=*(const float4*)&lk[0][e]; ak0 += x.x*w0 + x.y*w1 + x.z*w2 + x.w*w3;
    x=*(const float4*)&lk[1][e]; ak1 += x.x*w0 + x.y*w1 + x.z*w2 + x.w*w3;
    x=*(const float4*)&lk[2][e]; ak2 += x.x*w0 + x.y*w1 + x.z*w2 + x.w*w3;
    x=*(const float4*)&lk[3][e]; ak3 += x.x*w0 + x.y*w1 + x.z*w2 + x.w*w3;
  }
  covq[(s0+0)*D_+t] = aq0 + ga[(s0+0)*D_+t];
  covq[(s0+1)*D_+t] = aq1 + ga[(s0+1)*D_+t];
  covq[(s0+2)*D_+t] = aq2 + ga[(s0+2)*D_+t];
  covq[(s0+3)*D_+t] = aq3 + ga[(s0+3)*D_+t];
  covk[(s0+0)*D_+t] = ak0 + gb[(s0+0)*D_+t];
  covk[(s0+1)*D_+t] = ak1 + gb[(s0+1)*D_+t];
  covk[(s0+2)*D_+t] = ak2 + gb[(s0+2)*D_+t];
  covk[(s0+3)*D_+t] = ak3 + gb[(s0+3)*D_+t];
}

// K3: logits rows -> softmax -> E = A@V (4 rows/block), plus sum(E^2). grid 96 x 384
__global__ void k_attn(const float* __restrict__ covq, const float* __restrict__ covk,
                       const float* __restrict__ v, float* __restrict__ E,
                       double* __restrict__ acc){
  int b=blockIdx.x, t=threadIdx.x, i0=b*4;
  __shared__ float cq[4][D_];
  __shared__ float P[4][D_];
  __shared__ float wred[4][6];
  __shared__ float wred2[4][6];
  __shared__ float sred[6];
  for (int idx=t; idx<4*D_; idx+=384){
    int r=idx/D_, e=idx-r*D_;
    cq[r][e] = covq[(i0+r)*D_+e];
  }
  __syncthreads();
  float l0=0,l1=0,l2=0,l3=0;
  const float* ckt = covk + t*D_;
  for (int d=0; d<D_; d+=4){
    float4 c = *(const float4*)(ckt+d);
    float4 a;
    a=*(const float4*)&cq[0][d]; l0 += a.x*c.x + a.y*c.y + a.z*c.z + a.w*c.w;
    a=*(const float4*)&cq[1][d]; l1 += a.x*c.x + a.y*c.y + a.z*c.z + a.w*c.w;
    a=*(const float4*)&cq[2][d]; l2 += a.x*c.x + a.y*c.y + a.z*c.z + a.w*c.w;
    a=*(const float4*)&cq[3][d]; l3 += a.x*c.x + a.y*c.y + a.z*c.z + a.w*c.w;
  }
  const float isq = 0.05103103630798288f; // 1/sqrt(384)
  l0*=isq; l1*=isq; l2*=isq; l3*=isq;
  float m0=waveMax(l0), m1=waveMax(l1), m2=waveMax(l2), m3=waveMax(l3);
  int wid=t>>6, lane=t&63;
  if (lane==0){ wred[0][wid]=m0; wred[1][wid]=m1; wred[2][wid]=m2; wred[3][wid]=m3; }
  __syncthreads();
  float mx0=wred[0][0], mx1=wred[1][0], mx2=wred[2][0], mx3=wred[3][0];
  for (int w=1; w<6; w++){
    mx0=fmaxf(mx0,wred[0][w]); mx1=fmaxf(mx1,wred[1][w]);
    mx2=fmaxf(mx2,wred[2][w]); mx3=fmaxf(mx3,wred[3][w]);
  }
  float e0=expf(l0-mx0), e1=expf(l1-mx1), e2=expf(l2-mx2), e3=expf(l3-mx3);
  float s0=waveSum(e0), s1=waveSum(e1), s2=waveSum(e2), s3=waveSum(e3);
  if (lane==0){ wred2[0][wid]=s0; wred2[1][wid]=s1; wred2[2][wid]=s2; wred2[3][wid]=s3; }
  __syncthreads();
  float d0=0,d1=0,d2=0,d3=0;
  for (int w=0; w<6; w++){ d0+=wred2[0][w]; d1+=wred2[1][w]; d2+=wred2[2][w]; d3+=wred2[3][w]; }
  P[0][t]=e0/d0; P[1][t]=e1/d1; P[2][t]=e2/d2; P[3][t]=e3/d3;
  __syncthreads();
  float ea0=0,ea1=0,ea2=0,ea3=0;
  for (int t2=0; t2<D_; t2+=4){
    float v0 = v[(t2+0)*D_+t];
    float v1 = v[(t2+1)*D_+t];
    float v2 = v[(t2+2)*D_+t];
    float v3 = v[(t2+3)*D_+t];
    float4 p;
    p=*(const float4*)&P[0][t2]; ea0 += p.x*v0 + p.y*v1 + p.z*v2 + p.w*v3;
    p=*(const float4*)&P[1][t2]; ea1 += p.x*v0 + p.y*v1 + p.z*v2 + p.w*v3;
    p=*(const float4*)&P[2][t2]; ea2 += p.x*v0 + p.y*v1 + p.z*v2 + p.w*v3;
    p=*(const float4*)&P[3][t2]; ea3 += p.x*v0 + p.y*v1 + p.z*v2 + p.w*v3;
  }
  E[(i0+0)*D_+t]=ea0; E[(i0+1)*D_+t]=ea1; E[(i0+2)*D_+t]=ea2; E[(i0+3)*D_+t]=ea3;
  float se2 = ea0*ea0+ea1*ea1+ea2*ea2+ea3*ea3;
  se2 = waveSum(se2);
  if (lane==0) sred[wid]=se2;
  __syncthreads();
  if (t==0){
    float s=sred[0]+sred[1]+sred[2]+sred[3]+sred[4]+sred[5];
    atomicAdd(&acc[1],(double)s);
  }
}

// K4: interaction energy MLP (sum over rows of relu([cq,ck]@W1+b1)@W2). grid 96 x 384
__global__ void k_mlp(const float* __restrict__ covq, const float* __restrict__ covk,
                      const float* __restrict__ W1, const float* __restrict__ b1,
                      const float* __restrict__ W2, double* __restrict__ acc){
  int b=blockIdx.x, t=threadIdx.x, s0=b*4;
  __shared__ float comb[4][2*D_];
  __shared__ float sred[6];
  for (int idx=t; idx<4*D_; idx+=384){
    int r=idx/D_, e=idx-r*D_;
    comb[r][e]      = covq[(s0+r)*D_+e];
    comb[r][D_+e]   = covk[(s0+r)*D_+e];
  }
  __syncthreads();
  float h0=0,h1=0,h2=0,h3=0;
  for (int e=0; e<2*D_; e+=4){
    float w0=W1[(e+0)*D_+t], w1=W1[(e+1)*D_+t], w2=W1[(e+2)*D_+t], w3=W1[(e+3)*D_+t];
    float4 c;
    c=*(const float4*)&comb[0][e]; h0 += c.x*w0 + c.y*w1 + c.z*w2 + c.w*w3;
    c=*(const float4*)&comb[1][e]; h1 += c.x*w0 + c.y*w1 + c.z*w2 + c.w*w3;
    c=*(const float4*)&comb[2][e]; h2 += c.x*w0 + c.y*w1 + c.z*w2 + c.w*w3;
    c=*(const float4*)&comb[3][e]; h3 += c.x*w0 + c.y*w1 + c.z*w2 + c.w*w3;
  }
  float bb=b1[t], w2c=W2[t];
  h0=fmaxf(h0+bb,0.f); h1=fmaxf(h1+bb,0.f); h2=fmaxf(h2+bb,0.f); h3=fmaxf(h3+bb,0.f);
  float p = (h0+h1+h2+h3)*w2c;
  p = waveSum(p);
  int wid=t>>6, lane=t&63;
  if (lane==0) sred[wid]=p;
  __syncthreads();
  if (t==0) atomicAdd(&acc[4], (double)(sred[0]+sred[1]+sred[2]+sred[3]+sred[4]+sred[5]));
}

// K5: field_strength write + sum(F), sum(F^2). grid 2304 x 256 (s x 6 chunks of 64 i-rows)
__global__ void k_writeF(const float* __restrict__ ga, const float* __restrict__ gb,
                         const float* __restrict__ cm, float* __restrict__ outF,
                         double* __restrict__ acc){
  int bs = blockIdx.x/6, ch = blockIdx.x%6, i0 = ch*64, t = threadIdx.x;
  __shared__ float gbs[D_];
  __shared__ float gas[64];
  for (int d=t; d<D_; d+=256) gbs[d] = gb[bs*D_+d];
  if (t<64) gas[t] = ga[bs*D_+i0+t];
  __syncthreads();
  const float4* cm4 = (const float4*)(cm + i0*D_);
  const float4* gb4 = (const float4*)gbs;
  float4* o4 = (float4*)(outF + ((size_t)bs*S_ + i0)*D_);
  float sF=0.f, sF2=0.f;
  for (int f=t; f<64*96; f+=256){
    int il = f/96;
    int j4 = f - il*96;
    float a = gas[il];
    float4 g = gb4[j4];
    float4 c = cm4[f];
    float4 o;
    o.x = a - g.x + c.x; o.y = a - g.y + c.y;
    o.z = a - g.z + c.z; o.w = a - g.w + c.w;
    o4[f] = o;
    sF  += (o.x+o.y)+(o.z+o.w);
    sF2 += o.x*o.x + o.y*o.y + o.z*o.z + o.w*o.w;
  }
  sF = waveSum(sF); sF2 = waveSum(sF2);
  __shared__ float r1[4], r2[4];
  int wid=t>>6, lane=t&63;
  if (lane==0){ r1[wid]=sF; r2[wid]=sF2; }
  __syncthreads();
  if (t==0){
    atomicAdd(&acc[2], (double)(r1[0]+r1[1]+r1[2]+r1[3]));
    atomicAdd(&acc[3], (double)(r2[0]+r2[1]+r2[2]+r2[3]));
  }
}

// K6: evolved_field write (E replicated over s). grid 2304 x 256
__global__ void k_writeE(const float* __restrict__ E, float* __restrict__ outE){
  int bs = blockIdx.x/6, ch = blockIdx.x%6, i0 = ch*64, t = threadIdx.x;
  const float4* e4 = (const float4*)(E + i0*D_);
  float4* o4 = (float4*)(outE + ((size_t)bs*S_ + i0)*D_);
  for (int f=t; f<6144; f+=256) o4[f]=e4[f];
}

// K7: scalars + small vectors. 1 x 384
__global__ void k_fin(const double* __restrict__ acc, const float* __restrict__ coup,
                      const float* __restrict__ b2, float* __restrict__ out){
  int t = threadIdx.x;
  double init_e = acc[0], fin_e = acc[1], sF = acc[2], sF2 = acc[3], en = acc[4];
  float cons = (float)(fabs(fin_e - init_e)/(init_e + 1e-8));
  if (t < 384){
    out[OUT_FC + t] = 0.0f;     // field_curvature == 0 (evolved constant along s)
    out[OUT_CO + t] = cons;     // conservation, same for every s
  }
  if (t == 0){
    out[OUT_IE] = (float)en + 384.0f*b2[0];
    out[OUT_YM] = coup[0]*(float)sF2;
    out[OUT_GI] = 1.0f;         // std of softmax row sums ~ 1e-16 -> clip(1-std)=1
    out[OUT_CH] = 1.0f;         // corrcoef of single row
    out[OUT_TP] = (float)(sF/(6.283185307179586*384.0));
  }
}

extern "C" void kernel_launch(void* const* d_in, const int* in_sizes, int n_in,
                              void* d_out, int out_size, void* d_ws, size_t ws_size,
                              hipStream_t stream) {
  const float* q    = (const float*)d_in[0];
  const float* k    = (const float*)d_in[1];
  const float* v    = (const float*)d_in[2];
  // d_in[3] gauge_weights: cancels in softmax, unused
  const float* Wcov = (const float*)d_in[4];
  const float* coup = (const float*)d_in[5];
  const float* W1   = (const float*)d_in[6];
  const float* b1   = (const float*)d_in[7];
  const float* W2   = (const float*)d_in[8];
  const float* b2   = (const float*)d_in[9];
  float* out = (float*)d_out;
  float* ws  = (float*)d_ws;
  float* ga   = ws;
  float* gb   = ws + 1*SD_;
  float* cm   = ws + 2*SD_;
  float* cq   = ws + 3*SD_;
  float* ck   = ws + 4*SD_;
  float* E    = ws + 5*SD_;
  double* acc = (double*)(ws + 6*SD_);   // [q2, E2, sF, sF2, energy]

  hipMemsetAsync(acc, 0, 5*sizeof(double), stream);
  k_prep<<<dim3(384), dim3(128), 0, stream>>>(q, k, ga, gb, cm, acc);
  k_cov <<<dim3(96),  dim3(384), 0, stream>>>(q, k, Wcov, ga, gb, cq, ck);
  k_attn<<<dim3(96),  dim3(384), 0, stream>>>(cq, ck, v, E, acc);
  k_mlp <<<dim3(96),  dim3(384), 0, stream>>>(cq, ck, W1, b1, W2, acc);
  k_writeF<<<dim3(2304), dim3(256), 0, stream>>>(ga, gb, cm, out + OUT_FS, acc);
  k_writeE<<<dim3(2304), dim3(256), 0, stream>>>(E, out + OUT_EV);
  k_fin <<<dim3(1), dim3(384), 0, stream>>>(acc, coup, b2, out);
}

// Round 2
// 642.463 us; speedup vs baseline: 1.1245x; 1.1245x over previous
//
#include <hip/hip_runtime.h>

#define S_ 384
#define D_ 384
#define SD_ (384*384)

// output offsets (floats) in return order
#define OUT_EV 0
#define OUT_FS 56623104
#define OUT_IE 113246208
#define OUT_YM 113246209
#define OUT_FC 113246210
#define OUT_GI 113246594
#define OUT_CO 113246595
#define OUT_CH 113246979
#define OUT_TP 113246980

typedef __attribute__((ext_vector_type(4))) float f32x4;

__device__ __forceinline__ float waveSum(float v){
  v += __shfl_down(v,32); v += __shfl_down(v,16); v += __shfl_down(v,8);
  v += __shfl_down(v,4);  v += __shfl_down(v,2);  v += __shfl_down(v,1);
  return v;
}
__device__ __forceinline__ float waveMax(float v){
  v = fmaxf(v,__shfl_down(v,32)); v = fmaxf(v,__shfl_down(v,16)); v = fmaxf(v,__shfl_down(v,8));
  v = fmaxf(v,__shfl_down(v,4));  v = fmaxf(v,__shfl_down(v,2));  v = fmaxf(v,__shfl_down(v,1));
  return v;
}
__device__ __forceinline__ double waveSumD(double v){
  v += __shfl_down(v,32); v += __shfl_down(v,16); v += __shfl_down(v,8);
  v += __shfl_down(v,4);  v += __shfl_down(v,2);  v += __shfl_down(v,1);
  return v;
}

// K1: gradients ga/gb, row means -> cm, per-row sum(q^2) partial. grid 384 x 128
__global__ void k_prep(const float* __restrict__ q, const float* __restrict__ k,
                       float* __restrict__ ga, float* __restrict__ gb,
                       float* __restrict__ cm, float* __restrict__ pq2){
  int s = blockIdx.x, t = threadIdx.x;
  const float* qs = q + s*D_;
  const float* ks = k + s*D_;
  float sq=0.f, sk=0.f, sq2=0.f;
  for (int d=t; d<D_; d+=128){ float a=qs[d], b=ks[d]; sq+=a; sk+=b; sq2+=a*a; }
  sq = waveSum(sq); sk = waveSum(sk); sq2 = waveSum(sq2);
  __shared__ float red[3][2];
  int wid=t>>6, lane=t&63;
  if (lane==0){ red[0][wid]=sq; red[1][wid]=sk; red[2][wid]=sq2; }
  __syncthreads();
  float qmean = (red[0][0]+red[0][1]) * (1.0f/D_);
  float kmean = (red[1][0]+red[1][1]) * (1.0f/D_);
  if (t==0) pq2[s] = red[2][0]+red[2][1];
  int sm = (s==0)?0:s-1, sp=(s==S_-1)?S_-1:s+1;
  float sc = (s==0 || s==S_-1) ? 1.f : 0.5f;
  const float* qm=q+sm*D_; const float* qp=q+sp*D_;
  const float* km=k+sm*D_; const float* kp=k+sp*D_;
  for (int d=t; d<D_; d+=128){
    ga[s*D_+d] = (qp[d]-qm[d])*sc;
    gb[s*D_+d] = (kp[d]-km[d])*sc;
    cm[s*D_+d] = qs[d]*kmean - ks[d]*qmean;
  }
}

// K2: cov_q = ga + q@W, cov_k = gb + k@W (+ ckT transpose copy). grid 96 x 384
// Operand rows read via wave-uniform global loads (-> s_load), W coalesced.
__global__ void k_cov(const float* __restrict__ q, const float* __restrict__ kk,
                      const float* __restrict__ W,
                      const float* __restrict__ ga, const float* __restrict__ gb,
                      float* __restrict__ covq, float* __restrict__ covk,
                      float* __restrict__ covkT){
  int b=blockIdx.x, t=threadIdx.x, s0=b*4;
  const float* q0=q +(s0+0)*D_; const float* q1=q +(s0+1)*D_;
  const float* q2=q +(s0+2)*D_; const float* q3=q +(s0+3)*D_;
  const float* k0=kk+(s0+0)*D_; const float* k1=kk+(s0+1)*D_;
  const float* k2=kk+(s0+2)*D_; const float* k3=kk+(s0+3)*D_;
  float aq0=0,aq1=0,aq2=0,aq3=0, ak0=0,ak1=0,ak2=0,ak3=0;
  for (int e=0;e<D_;e+=4){
    float w0=W[(e+0)*D_+t], w1=W[(e+1)*D_+t], w2=W[(e+2)*D_+t], w3=W[(e+3)*D_+t];
    f32x4 x;
    x=*(const f32x4*)(q0+e); aq0 += x.x*w0 + x.y*w1 + x.z*w2 + x.w*w3;
    x=*(const f32x4*)(q1+e); aq1 += x.x*w0 + x.y*w1 + x.z*w2 + x.w*w3;
    x=*(const f32x4*)(q2+e); aq2 += x.x*w0 + x.y*w1 + x.z*w2 + x.w*w3;
    x=*(const f32x4*)(q3+e); aq3 += x.x*w0 + x.y*w1 + x.z*w2 + x.w*w3;
    x=*(const f32x4*)(k0+e); ak0 += x.x*w0 + x.y*w1 + x.z*w2 + x.w*w3;
    x=*(const f32x4*)(k1+e); ak1 += x.x*w0 + x.y*w1 + x.z*w2 + x.w*w3;
    x=*(const f32x4*)(k2+e); ak2 += x.x*w0 + x.y*w1 + x.z*w2 + x.w*w3;
    x=*(const f32x4*)(k3+e); ak3 += x.x*w0 + x.y*w1 + x.z*w2 + x.w*w3;
  }
  aq0 += ga[(s0+0)*D_+t]; aq1 += ga[(s0+1)*D_+t];
  aq2 += ga[(s0+2)*D_+t]; aq3 += ga[(s0+3)*D_+t];
  ak0 += gb[(s0+0)*D_+t]; ak1 += gb[(s0+1)*D_+t];
  ak2 += gb[(s0+2)*D_+t]; ak3 += gb[(s0+3)*D_+t];
  covq[(s0+0)*D_+t]=aq0; covq[(s0+1)*D_+t]=aq1;
  covq[(s0+2)*D_+t]=aq2; covq[(s0+3)*D_+t]=aq3;
  covk[(s0+0)*D_+t]=ak0; covk[(s0+1)*D_+t]=ak1;
  covk[(s0+2)*D_+t]=ak2; covk[(s0+3)*D_+t]=ak3;
  f32x4 tr; tr.x=ak0; tr.y=ak1; tr.z=ak2; tr.w=ak3;
  *(f32x4*)(covkT + t*D_ + s0) = tr;   // covkT[d][s]
}

// K3: logits (via ckT, coalesced) -> softmax -> E = A@V, E^2 partial. grid 96 x 384
__global__ void k_attn(const float* __restrict__ covq, const float* __restrict__ ckT,
                       const float* __restrict__ v, float* __restrict__ E,
                       float* __restrict__ pE2){
  int b=blockIdx.x, t=threadIdx.x, i0=b*4;
  __shared__ float P[4][D_];
  __shared__ float wred[4][6];
  __shared__ float wred2[4][6];
  __shared__ float sred[6];
  const float* q0=covq+(i0+0)*D_; const float* q1=covq+(i0+1)*D_;
  const float* q2=covq+(i0+2)*D_; const float* q3=covq+(i0+3)*D_;
  float l0=0,l1=0,l2=0,l3=0;
  for (int e=0;e<D_;e+=4){
    float c0=ckT[(e+0)*D_+t], c1=ckT[(e+1)*D_+t], c2=ckT[(e+2)*D_+t], c3=ckT[(e+3)*D_+t];
    f32x4 a;
    a=*(const f32x4*)(q0+e); l0 += a.x*c0 + a.y*c1 + a.z*c2 + a.w*c3;
    a=*(const f32x4*)(q1+e); l1 += a.x*c0 + a.y*c1 + a.z*c2 + a.w*c3;
    a=*(const f32x4*)(q2+e); l2 += a.x*c0 + a.y*c1 + a.z*c2 + a.w*c3;
    a=*(const f32x4*)(q3+e); l3 += a.x*c0 + a.y*c1 + a.z*c2 + a.w*c3;
  }
  const float isq = 0.05103103630798288f; // 1/sqrt(384)
  l0*=isq; l1*=isq; l2*=isq; l3*=isq;
  float m0=waveMax(l0), m1=waveMax(l1), m2=waveMax(l2), m3=waveMax(l3);
  int wid=t>>6, lane=t&63;
  if (lane==0){ wred[0][wid]=m0; wred[1][wid]=m1; wred[2][wid]=m2; wred[3][wid]=m3; }
  __syncthreads();
  float mx0=wred[0][0], mx1=wred[1][0], mx2=wred[2][0], mx3=wred[3][0];
  for (int w=1; w<6; w++){
    mx0=fmaxf(mx0,wred[0][w]); mx1=fmaxf(mx1,wred[1][w]);
    mx2=fmaxf(mx2,wred[2][w]); mx3=fmaxf(mx3,wred[3][w]);
  }
  float e0=expf(l0-mx0), e1=expf(l1-mx1), e2=expf(l2-mx2), e3=expf(l3-mx3);
  float s0=waveSum(e0), s1=waveSum(e1), s2=waveSum(e2), s3=waveSum(e3);
  if (lane==0){ wred2[0][wid]=s0; wred2[1][wid]=s1; wred2[2][wid]=s2; wred2[3][wid]=s3; }
  __syncthreads();
  float d0=0,d1=0,d2=0,d3=0;
  for (int w=0; w<6; w++){ d0+=wred2[0][w]; d1+=wred2[1][w]; d2+=wred2[2][w]; d3+=wred2[3][w]; }
  P[0][t]=e0/d0; P[1][t]=e1/d1; P[2][t]=e2/d2; P[3][t]=e3/d3;
  __syncthreads();
  float ea0=0,ea1=0,ea2=0,ea3=0;
  for (int t2=0; t2<D_; t2+=4){
    float v0 = v[(t2+0)*D_+t];
    float v1 = v[(t2+1)*D_+t];
    float v2 = v[(t2+2)*D_+t];
    float v3 = v[(t2+3)*D_+t];
    f32x4 p;
    p=*(const f32x4*)&P[0][t2]; ea0 += p.x*v0 + p.y*v1 + p.z*v2 + p.w*v3;
    p=*(const f32x4*)&P[1][t2]; ea1 += p.x*v0 + p.y*v1 + p.z*v2 + p.w*v3;
    p=*(const f32x4*)&P[2][t2]; ea2 += p.x*v0 + p.y*v1 + p.z*v2 + p.w*v3;
    p=*(const f32x4*)&P[3][t2]; ea3 += p.x*v0 + p.y*v1 + p.z*v2 + p.w*v3;
  }
  E[(i0+0)*D_+t]=ea0; E[(i0+1)*D_+t]=ea1; E[(i0+2)*D_+t]=ea2; E[(i0+3)*D_+t]=ea3;
  float se2 = ea0*ea0+ea1*ea1+ea2*ea2+ea3*ea3;
  se2 = waveSum(se2);
  if (lane==0) sred[wid]=se2;
  __syncthreads();
  if (t==0) pE2[b] = sred[0]+sred[1]+sred[2]+sred[3]+sred[4]+sred[5];
}

// K4: interaction energy MLP partials. grid 96 x 384
__global__ void k_mlp(const float* __restrict__ covq, const float* __restrict__ covk,
                      const float* __restrict__ W1, const float* __restrict__ b1,
                      const float* __restrict__ W2, float* __restrict__ pen){
  int b=blockIdx.x, t=threadIdx.x, s0=b*4;
  __shared__ float sred[6];
  const float* c0=covq+(s0+0)*D_; const float* c1=covq+(s0+1)*D_;
  const float* c2=covq+(s0+2)*D_; const float* c3=covq+(s0+3)*D_;
  const float* d0=covk+(s0+0)*D_; const float* d1=covk+(s0+1)*D_;
  const float* d2=covk+(s0+2)*D_; const float* d3=covk+(s0+3)*D_;
  float h0=0,h1=0,h2=0,h3=0;
  for (int e=0; e<D_; e+=4){
    float w0=W1[(e+0)*D_+t], w1=W1[(e+1)*D_+t], w2=W1[(e+2)*D_+t], w3=W1[(e+3)*D_+t];
    f32x4 x;
    x=*(const f32x4*)(c0+e); h0 += x.x*w0 + x.y*w1 + x.z*w2 + x.w*w3;
    x=*(const f32x4*)(c1+e); h1 += x.x*w0 + x.y*w1 + x.z*w2 + x.w*w3;
    x=*(const f32x4*)(c2+e); h2 += x.x*w0 + x.y*w1 + x.z*w2 + x.w*w3;
    x=*(const f32x4*)(c3+e); h3 += x.x*w0 + x.y*w1 + x.z*w2 + x.w*w3;
  }
  for (int e=0; e<D_; e+=4){
    float w0=W1[(D_+e+0)*D_+t], w1=W1[(D_+e+1)*D_+t], w2=W1[(D_+e+2)*D_+t], w3=W1[(D_+e+3)*D_+t];
    f32x4 x;
    x=*(const f32x4*)(d0+e); h0 += x.x*w0 + x.y*w1 + x.z*w2 + x.w*w3;
    x=*(const f32x4*)(d1+e); h1 += x.x*w0 + x.y*w1 + x.z*w2 + x.w*w3;
    x=*(const f32x4*)(d2+e); h2 += x.x*w0 + x.y*w1 + x.z*w2 + x.w*w3;
    x=*(const f32x4*)(d3+e); h3 += x.x*w0 + x.y*w1 + x.z*w2 + x.w*w3;
  }
  float bb=b1[t], w2c=W2[t];
  h0=fmaxf(h0+bb,0.f); h1=fmaxf(h1+bb,0.f); h2=fmaxf(h2+bb,0.f); h3=fmaxf(h3+bb,0.f);
  float p = (h0+h1+h2+h3)*w2c;
  p = waveSum(p);
  int wid=t>>6, lane=t&63;
  if (lane==0) sred[wid]=p;
  __syncthreads();
  if (t==0) pen[b] = sred[0]+sred[1]+sred[2]+sred[3]+sred[4]+sred[5];
}

// K5: row/col sums of ga, gb, cm for the algebraic F-reduction. grid 384 x 384
__global__ void k_sums(const float* __restrict__ ga, const float* __restrict__ gb,
                       const float* __restrict__ cm,
                       float* __restrict__ Sga, float* __restrict__ Sgb,
                       float* __restrict__ Rcm, float* __restrict__ P2,
                       float* __restrict__ Cga, float* __restrict__ Cgb,
                       float* __restrict__ Ccm){
  int b=blockIdx.x, t=threadIdx.x;
  float ra=ga[b*D_+t], rg=gb[b*D_+t], rc=cm[b*D_+t];   // row b (coalesced)
  float ca=ga[t*D_+b], cg=gb[t*D_+b], cc=cm[t*D_+b];   // col b
  float p2 = ra*ra + rg*rg + rc*rc;
  float s0=waveSum(ra), s1=waveSum(rg), s2=waveSum(rc), s3=waveSum(p2);
  float s4=waveSum(ca), s5=waveSum(cg), s6=waveSum(cc);
  __shared__ float red[7][6];
  int wid=t>>6, lane=t&63;
  if (lane==0){ red[0][wid]=s0; red[1][wid]=s1; red[2][wid]=s2; red[3][wid]=s3;
                red[4][wid]=s4; red[5][wid]=s5; red[6][wid]=s6; }
  __syncthreads();
  if (t==0){
    float a0=0,a1=0,a2=0,a3=0,a4=0,a5=0,a6=0;
    for (int w=0;w<6;w++){ a0+=red[0][w]; a1+=red[1][w]; a2+=red[2][w]; a3+=red[3][w];
                           a4+=red[4][w]; a5+=red[5][w]; a6+=red[6][w]; }
    Sga[b]=a0; Sgb[b]=a1; Rcm[b]=a2; P2[b]=a3; Cga[b]=a4; Cgb[b]=a5; Ccm[b]=a6;
  }
}

// K6: final scalars + small vectors. 1 x 384
// sumF  = 384*(Sga_tot - Sgb_tot + Rcm_tot)
// sumF2 = 384*P2_tot - 2*sum_s Sga*Sgb + 2*sum_i Cga*Rcm - 2*sum_j Cgb*Ccm
__global__ void k_fin(const float* __restrict__ pq2,
                      const float* __restrict__ Sga, const float* __restrict__ Sgb,
                      const float* __restrict__ Rcm, const float* __restrict__ P2,
                      const float* __restrict__ Cga, const float* __restrict__ Cgb,
                      const float* __restrict__ Ccm,
                      const float* __restrict__ pE2, const float* __restrict__ pen,
                      const float* __restrict__ coup, const float* __restrict__ b2,
                      float* __restrict__ out){
  int t = threadIdx.x;
  double v[10];
  v[0]=pq2[t];
  v[1]=Sga[t]; v[2]=Sgb[t]; v[3]=Rcm[t]; v[4]=P2[t];
  v[5]=(double)Sga[t]*Sgb[t];
  v[6]=(double)Cga[t]*Rcm[t];
  v[7]=(double)Cgb[t]*Ccm[t];
  v[8]=(t<96)? (double)pE2[t] : 0.0;
  v[9]=(t<96)? (double)pen[t] : 0.0;
  __shared__ double red[10][6];
  int wid=t>>6, lane=t&63;
  #pragma unroll
  for (int i=0;i<10;i++){
    double s = waveSumD(v[i]);
    if (lane==0) red[i][wid]=s;
  }
  __syncthreads();
  double tot[10];
  #pragma unroll
  for (int i=0;i<10;i++){
    double s=0; for (int w=0;w<6;w++) s+=red[i][w];
    tot[i]=s;
  }
  double init_e=tot[0], fin_e=tot[8], en=tot[9];
  double sumF  = 384.0*(tot[1]-tot[2]+tot[3]);
  double sumF2 = 384.0*tot[4] - 2.0*tot[5] + 2.0*tot[6] - 2.0*tot[7];
  float cons = (float)(fabs(fin_e - init_e)/(init_e + 1e-8));
  out[OUT_FC + t] = 0.0f;    // evolved constant along s -> second gradient == 0
  out[OUT_CO + t] = cons;
  if (t == 0){
    out[OUT_IE] = (float)en + 384.0f*b2[0];
    out[OUT_YM] = coup[0]*(float)sumF2;
    out[OUT_GI] = 1.0f;      // softmax row sums == 1 -> std ~ 0 -> clip = 1
    out[OUT_CH] = 1.0f;      // corrcoef of single row
    out[OUT_TP] = (float)(sumF/(6.283185307179586*384.0));
  }
}

// K7: both big streaming writes, no reductions, nontemporal stores. grid 4608 x 256
__global__ __launch_bounds__(256) void
k_write(const float* __restrict__ ga, const float* __restrict__ gb,
        const float* __restrict__ cm, const float* __restrict__ E,
        float* __restrict__ outF, float* __restrict__ outE){
  int id = blockIdx.x, t = threadIdx.x;
  __shared__ float gbs[D_];
  __shared__ float gas[64];
  if (id < 2304){
    int bs = id/6, ch = id%6, i0 = ch*64;
    for (int d=t; d<D_; d+=256) gbs[d] = gb[bs*D_+d];
    if (t<64) gas[t] = ga[bs*D_+i0+t];
    __syncthreads();
    const f32x4* cm4 = (const f32x4*)(cm + i0*D_);
    const f32x4* gb4 = (const f32x4*)gbs;
    f32x4* o4 = (f32x4*)(outF + ((size_t)bs*S_ + i0)*D_);
    for (int f=t; f<6144; f+=256){
      int il = f/96;
      int j4 = f - il*96;
      float a = gas[il];
      f32x4 g = gb4[j4];
      f32x4 c = cm4[f];
      f32x4 o = a - g + c;
      __builtin_nontemporal_store(o, o4+f);
    }
  } else {
    id -= 2304;
    int bs = id/6, ch = id%6, i0 = ch*64;
    const f32x4* e4 = (const f32x4*)(E + i0*D_);
    f32x4* o4 = (f32x4*)(outE + ((size_t)bs*S_ + i0)*D_);
    for (int f=t; f<6144; f+=256)
      __builtin_nontemporal_store(e4[f], o4+f);
  }
}

extern "C" void kernel_launch(void* const* d_in, const int* in_sizes, int n_in,
                              void* d_out, int out_size, void* d_ws, size_t ws_size,
                              hipStream_t stream) {
  const float* q    = (const float*)d_in[0];
  const float* k    = (const float*)d_in[1];
  const float* v    = (const float*)d_in[2];
  // d_in[3] gauge_weights: cancels in softmax, unused
  const float* Wcov = (const float*)d_in[4];
  const float* coup = (const float*)d_in[5];
  const float* W1   = (const float*)d_in[6];
  const float* b1   = (const float*)d_in[7];
  const float* W2   = (const float*)d_in[8];
  const float* b2   = (const float*)d_in[9];
  float* out = (float*)d_out;
  float* ws  = (float*)d_ws;
  float* ga   = ws;
  float* gb   = ws + 1*SD_;
  float* cm   = ws + 2*SD_;
  float* cq   = ws + 3*SD_;
  float* ck   = ws + 4*SD_;
  float* ckT  = ws + 5*SD_;
  float* E    = ws + 6*SD_;
  float* base = ws + 7*SD_;
  float* pq2 = base;        // 384
  float* Sga = base + 384;  float* Sgb = base + 768;
  float* Rcm = base + 1152; float* P2  = base + 1536;
  float* Cga = base + 1920; float* Cgb = base + 2304;
  float* Ccm = base + 2688;
  float* pE2 = base + 3072; // 96
  float* pen = base + 3168; // 96

  k_prep <<<dim3(384),  dim3(128), 0, stream>>>(q, k, ga, gb, cm, pq2);
  k_cov  <<<dim3(96),   dim3(384), 0, stream>>>(q, k, Wcov, ga, gb, cq, ck, ckT);
  k_attn <<<dim3(96),   dim3(384), 0, stream>>>(cq, ckT, v, E, pE2);
  k_mlp  <<<dim3(96),   dim3(384), 0, stream>>>(cq, ck, W1, b1, W2, pen);
  k_sums <<<dim3(384),  dim3(384), 0, stream>>>(ga, gb, cm, Sga, Sgb, Rcm, P2, Cga, Cgb, Ccm);
  k_fin  <<<dim3(1),    dim3(384), 0, stream>>>(pq2, Sga, Sgb, Rcm, P2, Cga, Cgb, Ccm,
                                                pE2, pen, coup, b2, out);
  k_write<<<dim3(4608), dim3(256), 0, stream>>>(ga, gb, cm, E, out + OUT_FS, out + OUT_EV);
}